// Round 7
// baseline (5490.341 us; speedup 1.0000x reference)
//
#include <hip/hip_runtime.h>
#include <stdint.h>
#include <cstdio>

typedef unsigned short u16;
typedef __attribute__((ext_vector_type(8))) __bf16 bf16x8;
typedef __attribute__((ext_vector_type(4))) float f32x4;
typedef __attribute__((ext_vector_type(4))) int i32x4;

#define AGENT __HIP_MEMORY_SCOPE_AGENT

__device__ __forceinline__ float bf2f(u16 u) {
  unsigned int x = ((unsigned int)u) << 16;
  return __builtin_bit_cast(float, x);
}
__device__ __forceinline__ u16 f2bf(float f) {
  unsigned int x = __builtin_bit_cast(unsigned int, f);
  unsigned int r = (x + 0x7fffu + ((x >> 16) & 1u)) >> 16;
  return (u16)r;
}
__device__ __forceinline__ float sigm(float x) { return 1.f / (1.f + __expf(-x)); }
__device__ __forceinline__ float tanh_f(float x) { return 1.f - 2.f / (__expf(2.f * x) + 1.f); }

// ---------- fp32 -> bf16 convert (x) ----------
__global__ __launch_bounds__(256) void k_cvt(const float* __restrict__ in, u16* __restrict__ out, int n4) {
  int i = blockIdx.x * 256 + threadIdx.x;
  if (i >= n4) return;
  float4 f = ((const float4*)in)[i];
  ushort4 o;
  o.x = f2bf(f.x); o.y = f2bf(f.y); o.z = f2bf(f.z); o.w = f2bf(f.w);
  ((ushort4*)out)[i] = o;
}

// ---------- pack Wx [768][3072] -> B-fragment order [nt=192][kt=24][lane=64][j=8] ----------
__global__ __launch_bounds__(256) void k_pack_wx(const float* __restrict__ Wx, u16* __restrict__ Bp) {
  int idx = blockIdx.x * 256 + threadIdx.x;
  if (idx >= 2359296) return;
  int j = idx & 7;
  int l = (idx >> 3) & 63;
  int t = idx >> 9;          // nt*24 + kt
  int kt = t % 24, nt = t / 24;
  int k = kt * 32 + (l >> 4) * 8 + j;
  int n = nt * 16 + (l & 15);
  Bp[idx] = f2bf(Wx[(size_t)k * 3072 + n]);
}

// ---------- pack Wh -> per-member slices [w=32][nt=6][kt=24][lane=64][j=8] ----------
// col order within 16-col tile: cc = 4*vi + q (vi = unit-in-wave 0..3, q = gate 0..3)
__global__ __launch_bounds__(256) void k_pack_wh(const float* __restrict__ Wh, u16* __restrict__ Wp) {
  int idx = blockIdx.x * 256 + threadIdx.x;
  if (idx >= 2359296) return;
  int j = idx & 7;
  int l = (idx >> 3) & 63;
  int t = idx >> 9;          // w*144 + nt*24 + kt
  int kt = t % 24;
  int tmp = t / 24;          // w*6 + nt
  int nt = tmp % 6, w = tmp / 6;
  int k = kt * 32 + (l >> 4) * 8 + j;
  int cc = l & 15;
  int vi = cc >> 2, q = cc & 3;
  int gcol = q * 768 + w * 24 + nt * 4 + vi;
  Wp[idx] = f2bf(Wh[(size_t)k * 3072 + gcol]);
}

// ---------- GEMM: C[16384][3072] bf16 = A[16384][768] bf16 @ Bp(packed) ----------
__global__ __launch_bounds__(256, 2) void k_gemm(const u16* __restrict__ A, const u16* __restrict__ Bp,
                                                 u16* __restrict__ C) {
  const int bid = blockIdx.x;
  const int bm = bid & 127, bn = bid >> 7;   // 128 x 24
  const int tid = threadIdx.x, lane = tid & 63, wv = tid >> 6;
  const int wm = wv >> 1, wn = wv & 1;
  const int row0 = bm * 128 + wm * 64;
  const int col0 = bn * 128 + wn * 64;
  const int rlo = lane & 15, rhi = lane >> 4;
  f32x4 acc[4][4] = {};
  const u16* Ab = A + (size_t)(row0 + rlo) * 768 + rhi * 8;
  const u16* Bb = Bp + ((size_t)(bn * 8 + wn * 4) * 24 * 64 + lane) * 8;
#pragma unroll 2
  for (int kt = 0; kt < 24; ++kt) {
    bf16x8 a[4], b[4];
#pragma unroll
    for (int i = 0; i < 4; ++i) a[i] = *(const bf16x8*)(Ab + (size_t)i * 16 * 768 + kt * 32);
#pragma unroll
    for (int j = 0; j < 4; ++j) b[j] = *(const bf16x8*)(Bb + (size_t)j * 24 * 64 * 8 + (size_t)kt * 64 * 8);
#pragma unroll
    for (int i = 0; i < 4; ++i)
#pragma unroll
      for (int j = 0; j < 4; ++j)
        acc[i][j] = __builtin_amdgcn_mfma_f32_16x16x32_bf16(a[i], b[j], acc[i][j], 0, 0, 0);
  }
#pragma unroll
  for (int i = 0; i < 4; ++i)
#pragma unroll
    for (int j = 0; j < 4; ++j)
#pragma unroll
      for (int r = 0; r < 4; ++r) {
        int row = row0 + i * 16 + rhi * 4 + r;
        int col = col0 + j * 16 + rlo;
        C[(size_t)row * 3072 + col] = f2bf(acc[i][j][r]);
      }
}

// ---------- persistent LSTM recurrence ----------
// 256 WGs x 384 threads (6 waves). Logical groups: g = wid&7 (4 seqs), member w = wid>>3 (24 units).
// Wave wv owns units [wv*4, wv*4+4): its 16 MFMA cols = 4 gates x 4 units (col = 4*vi + q).
// Per step: merged poll+fetch (tagged, s_sleep backoff) -> stage hlds[t&1] -> raw barrier
// (lgkm-only drain; publish/hout/xg vmem stays in flight) -> MFMA (4 indep chains) ->
// wave-local 16x4 transpose -> cell math -> fire-and-forget tagged publish.
__global__ __launch_bounds__(384) void k_rec(
    const u16* __restrict__ xg,    // [16384][3072] bf16, m = seq*512 + t
    const u16* __restrict__ Whp,   // [32][6][24][64][8] packed bf16
    const float* __restrict__ bias,
    int* hbuf,                     // [8 groups][2][3072] tagged dwords (zeroed)
    u16* __restrict__ hout_bf,     // layer 0 out (bf16) or null
    float* __restrict__ hout_f,    // layer 1 out (fp32) or null
    int layer) {
  __shared__ __align__(16) int hlds[2][4 * 400];  // double-buffered h_{t-1}[4 seq][768]
  __shared__ __align__(16) float wlds[6][68];     // per-wave 16x4 gate transpose scratch

  const int wid = blockIdx.x, g = wid & 7, w = wid >> 3;
  const int tid = threadIdx.x, lane = tid & 63, wv = tid >> 6;

  // ---- Wh fragments -> registers (static indices) ----
  bf16x8 bregE[12], bregO[12];
  {
    const u16* bp = Whp + (((size_t)(w * 6 + wv) * 24) * 64 + lane) * 8;
#pragma unroll
    for (int kk = 0; kk < 12; ++kk) {
      bregE[kk] = *(const bf16x8*)(bp + (size_t)(2 * kk) * 512);
      bregO[kk] = *(const bf16x8*)(bp + (size_t)(2 * kk + 1) * 512);
    }
  }

  // ---- cell role: lanes 0-15 of each wave own cell (seq r, unit vi) ----
  const bool cellt = lane < 16;
  const int vi = lane & 3, r = (lane >> 2) & 3;
  const int unit = w * 24 + wv * 4 + vi;
  const int seq = g * 4 + r;
  float bv0 = 0, bv1 = 0, bv2 = 0, bv3 = 0, xv0 = 0, xv1 = 0, xv2 = 0, xv3 = 0;
  if (cellt) {
    bv0 = bias[unit]; bv1 = bias[768 + unit]; bv2 = bias[1536 + unit]; bv3 = bias[2304 + unit];
    const u16* xr = xg + (size_t)seq * 512 * 3072;
    xv0 = bf2f(xr[unit]); xv1 = bf2f(xr[768 + unit]);
    xv2 = bf2f(xr[1536 + unit]); xv3 = bf2f(xr[2304 + unit]);
  }
  float cst = 0.f;
  const int sl = (lane & 15) < 4 ? (lane & 15) : 3;      // A-frag row (pad rows clamped)
  const int abase = sl * 400 + (lane >> 4) * 4;          // A-frag dword base within buffer
  const int c = tid;                                     // poll chunk id (8 dwords)
  const int hrow = c / 96, hcol = (c % 96) * 4;          // staged int4 slot
  int guard = 0;

  __syncthreads();

  for (int t = 0; t < 512; ++t) {
    int* hb = hlds[t & 1];
    // ---- merged poll+fetch of h_{t-1} with sleep backoff (1 LLC RT on success) ----
    const int expect = t;  // tag from step t-1 producers (t=0: zeroed buffer)
    int* src = hbuf + (size_t)(g * 2 + (t & 1)) * 3072;
    const int* p0 = src + 8 * c;
    const int* p1 = src + 8 * c + 4;
    i32x4 v0, v1;
    for (;;) {
      asm volatile("global_load_dwordx4 %0, %2, off sc0 sc1\n\t"
                   "global_load_dwordx4 %1, %3, off sc0 sc1\n\t"
                   "s_waitcnt vmcnt(0)"
                   : "=&v"(v0), "=&v"(v1)
                   : "v"(p0), "v"(p1)
                   : "memory");
      bool ok = true;
#pragma unroll
      for (int j = 0; j < 4; ++j)
        ok = ok && ((v0[j] & 0xffff) == expect) && ((v1[j] & 0xffff) == expect);
      if (ok || ++guard > (1 << 22)) break;
      __builtin_amdgcn_s_sleep(1);  // back off: cut LLC re-poll bandwidth
    }
    // stage packed bf16 pairs into hlds[t&1]
    {
      int4 pk;
      pk.x = (int)(((unsigned)v0[0] >> 16) | ((unsigned)v0[1] & 0xffff0000u));
      pk.y = (int)(((unsigned)v0[2] >> 16) | ((unsigned)v0[3] & 0xffff0000u));
      pk.z = (int)(((unsigned)v1[0] >> 16) | ((unsigned)v1[1] & 0xffff0000u));
      pk.w = (int)(((unsigned)v1[2] >> 16) | ((unsigned)v1[3] & 0xffff0000u));
      *(int4*)&hb[hrow * 400 + hcol] = pk;
    }
    // xg prefetch for t+1: issue now, consume at end of cell (hidden under MFMA)
    u16 n0 = 0, n1 = 0, n2 = 0, n3 = 0;
    if (cellt && t + 1 < 512) {
      const u16* xr = xg + ((size_t)seq * 512 + t + 1) * 3072;
      n0 = xr[unit]; n1 = xr[768 + unit]; n2 = xr[1536 + unit]; n3 = xr[2304 + unit];
    }
    // raw barrier: drain LDS only — publish/hout/xg vmem stays in flight
    asm volatile("s_waitcnt lgkmcnt(0)\n\ts_barrier" ::: "memory");

    // ---- MFMA: gates[4 seq][16 cols of wave tile], 4 independent chains of 6 ----
    f32x4 a0 = {0, 0, 0, 0}, a1 = {0, 0, 0, 0}, a2 = {0, 0, 0, 0}, a3 = {0, 0, 0, 0};
#pragma unroll
    for (int kk = 0; kk < 12; kk += 2) {
      bf16x8 e0 = *(const bf16x8*)(hb + abase + (2 * kk) * 16);
      bf16x8 o0 = *(const bf16x8*)(hb + abase + (2 * kk + 1) * 16);
      bf16x8 e1 = *(const bf16x8*)(hb + abase + (2 * kk + 2) * 16);
      bf16x8 o1 = *(const bf16x8*)(hb + abase + (2 * kk + 3) * 16);
      a0 = __builtin_amdgcn_mfma_f32_16x16x32_bf16(e0, bregE[kk], a0, 0, 0, 0);
      a1 = __builtin_amdgcn_mfma_f32_16x16x32_bf16(o0, bregO[kk], a1, 0, 0, 0);
      a2 = __builtin_amdgcn_mfma_f32_16x16x32_bf16(e1, bregE[kk + 1], a2, 0, 0, 0);
      a3 = __builtin_amdgcn_mfma_f32_16x16x32_bf16(o1, bregO[kk + 1], a3, 0, 0, 0);
    }
    a0 = (a0 + a2) + (a1 + a3);

    // ---- wave-local 16x4 transpose -> cell lanes (no WG barrier) ----
    if (cellt) {
#pragma unroll
      for (int rr = 0; rr < 4; ++rr) wlds[wv][rr * 16 + lane] = a0[rr];
    }
    asm volatile("s_waitcnt lgkmcnt(0)" ::: "memory");
    if (cellt) {
      f32x4 tr = *(const f32x4*)&wlds[wv][r * 16 + vi * 4];  // gates i,f,g,o
      float p0g = xv0 + tr[0] + bv0;
      float p1g = xv1 + tr[1] + bv1;
      float p2g = xv2 + tr[2] + bv2;
      float p3g = xv3 + tr[3] + bv3;
      float ig = sigm(p0g), fg = sigm(p1g), gg = tanh_f(p2g), og = sigm(p3g);
      cst = fg * cst + ig * gg;
      float h = og * tanh_f(cst);
      // publish tagged h (fire-and-forget; dword atomicity makes it self-validating)
      int* dst = hbuf + (size_t)(g * 2 + ((t + 1) & 1)) * 3072 + r * 768 + unit;
      int val = (int)(((unsigned)f2bf(h) << 16) | (unsigned)(t + 1));
      __hip_atomic_store(dst, val, __ATOMIC_RELAXED, AGENT);
      // off the critical path: output store + swap in prefetched xg
      size_t o = ((size_t)seq * 512 + t) * 768 + unit;
      if (layer == 0) hout_bf[o] = f2bf(h); else hout_f[o] = h;
      if (t + 1 < 512) {
        xv0 = bf2f(n0); xv1 = bf2f(n1); xv2 = bf2f(n2); xv3 = bf2f(n3);
      }
    }
  }
}

// ---------- LayerNorm (in-place safe) ----------
__global__ __launch_bounds__(256) void k_ln(const float* __restrict__ in, const float* __restrict__ sc,
                                            const float* __restrict__ bi, float* __restrict__ out) {
  const int row = blockIdx.x, tid = threadIdx.x;
  const float* x = in + (size_t)row * 768;
  float v0 = x[tid], v1 = x[tid + 256], v2 = x[tid + 512];
  float s = v0 + v1 + v2;
  float s2 = v0 * v0 + v1 * v1 + v2 * v2;
#pragma unroll
  for (int off = 32; off >= 1; off >>= 1) {
    s += __shfl_xor(s, off);
    s2 += __shfl_xor(s2, off);
  }
  __shared__ float red[8];
  const int wv = tid >> 6;
  if ((tid & 63) == 0) { red[wv] = s; red[4 + wv] = s2; }
  __syncthreads();
  s = red[0] + red[1] + red[2] + red[3];
  s2 = red[4] + red[5] + red[6] + red[7];
  float mean = s * (1.f / 768.f);
  float var = s2 * (1.f / 768.f) - mean * mean;
  float rs = rsqrtf(var + 1e-6f);
  float* o = out + (size_t)row * 768;
  o[tid] = (v0 - mean) * rs * sc[tid] + bi[tid];
  o[tid + 256] = (v1 - mean) * rs * sc[tid + 256] + bi[tid + 256];
  o[tid + 512] = (v2 - mean) * rs * sc[tid + 512] + bi[tid + 512];
}

extern "C" void kernel_launch(void* const* d_in, const int* in_sizes, int n_in,
                              void* d_out, int out_size, void* d_ws, size_t ws_size,
                              hipStream_t stream) {
  const float* x   = (const float*)d_in[0];
  const float* Wx0 = (const float*)d_in[1];
  const float* Wh0 = (const float*)d_in[2];
  const float* b0  = (const float*)d_in[3];
  const float* Wx1 = (const float*)d_in[4];
  const float* Wh1 = (const float*)d_in[5];
  const float* b1  = (const float*)d_in[6];
  const float* lns = (const float*)d_in[7];
  const float* lnb = (const float*)d_in[8];
  float* out = (float*)d_out;

  char* p = (char*)d_ws;
  auto alloc = [&](size_t bytes) {
    char* r = p;
    p += (bytes + 255) & ~(size_t)255;
    return r;
  };
  u16* xg    = (u16*)alloc(16384ull * 3072 * 2);
  u16* xbf   = (u16*)alloc(16384ull * 768 * 2);
  u16* h0bf  = (u16*)alloc(16384ull * 768 * 2);
  u16* Wxp0  = (u16*)alloc(2359296ull * 2);
  u16* Wxp1  = (u16*)alloc(2359296ull * 2);
  u16* Whp0  = (u16*)alloc(2359296ull * 2);
  u16* Whp1  = (u16*)alloc(2359296ull * 2);
  char* sync0 = alloc(196608ull * 2);   // hbuf0, hbuf1 (tagged dwords)
  int* hbuf0 = (int*)sync0;
  int* hbuf1 = (int*)(sync0 + 196608);

  if ((size_t)(p - (char*)d_ws) > ws_size) {
    fprintf(stderr, "kernel_launch: ws too small: need %zu have %zu\n",
            (size_t)(p - (char*)d_ws), ws_size);
    return;
  }

  hipMemsetAsync(sync0, 0, 196608ull * 2, stream);
  k_cvt<<<12288, 256, 0, stream>>>(x, xbf, 3145728);
  k_pack_wx<<<9216, 256, 0, stream>>>(Wx0, Wxp0);
  k_pack_wx<<<9216, 256, 0, stream>>>(Wx1, Wxp1);
  k_pack_wh<<<9216, 256, 0, stream>>>(Wh0, Whp0);
  k_pack_wh<<<9216, 256, 0, stream>>>(Wh1, Whp1);

  k_gemm<<<3072, 256, 0, stream>>>(xbf, Wxp0, xg);
  k_rec<<<256, 384, 0, stream>>>(xg, Whp0, b0, hbuf0, h0bf, nullptr, 0);
  k_gemm<<<3072, 256, 0, stream>>>(h0bf, Wxp1, xg);
  k_rec<<<256, 384, 0, stream>>>(xg, Whp1, b1, hbuf1, nullptr, (float*)d_out, 1);
  k_ln<<<16384, 256, 0, stream>>>((const float*)d_out, lns, lnb, out);
}

// Round 8
// 2180.595 us; speedup vs baseline: 2.5178x; 2.5178x over previous
//
#include <hip/hip_runtime.h>
#include <stdint.h>
#include <cstdio>

typedef unsigned short u16;
typedef __attribute__((ext_vector_type(8))) __bf16 bf16x8;
typedef __attribute__((ext_vector_type(4))) float f32x4;
typedef __attribute__((ext_vector_type(4))) int i32x4;

#define AGENT __HIP_MEMORY_SCOPE_AGENT

__device__ __forceinline__ float bf2f(u16 u) {
  unsigned int x = ((unsigned int)u) << 16;
  return __builtin_bit_cast(float, x);
}
__device__ __forceinline__ u16 f2bf(float f) {
  unsigned int x = __builtin_bit_cast(unsigned int, f);
  unsigned int r = (x + 0x7fffu + ((x >> 16) & 1u)) >> 16;
  return (u16)r;
}
__device__ __forceinline__ float sigm(float x) { return 1.f / (1.f + __expf(-x)); }
__device__ __forceinline__ float tanh_f(float x) { return 1.f - 2.f / (__expf(2.f * x) + 1.f); }

// ---------- fp32 -> bf16 convert (x) ----------
__global__ __launch_bounds__(256) void k_cvt(const float* __restrict__ in, u16* __restrict__ out, int n4) {
  int i = blockIdx.x * 256 + threadIdx.x;
  if (i >= n4) return;
  float4 f = ((const float4*)in)[i];
  ushort4 o;
  o.x = f2bf(f.x); o.y = f2bf(f.y); o.z = f2bf(f.z); o.w = f2bf(f.w);
  ((ushort4*)out)[i] = o;
}

// ---------- pack Wx [768][3072] -> B-fragment order [nt=192][kt=24][lane=64][j=8] ----------
__global__ __launch_bounds__(256) void k_pack_wx(const float* __restrict__ Wx, u16* __restrict__ Bp) {
  int idx = blockIdx.x * 256 + threadIdx.x;
  if (idx >= 2359296) return;
  int j = idx & 7;
  int l = (idx >> 3) & 63;
  int t = idx >> 9;          // nt*24 + kt
  int kt = t % 24, nt = t / 24;
  int k = kt * 32 + (l >> 4) * 8 + j;
  int n = nt * 16 + (l & 15);
  Bp[idx] = f2bf(Wx[(size_t)k * 3072 + n]);
}

// ---------- pack Wh -> per-member slices [w=32][nt=6][kt=24][lane=64][j=8] ----------
// col order within 16-col tile: cc = 4*vi + q (vi = unit-in-wave 0..3, q = gate 0..3)
__global__ __launch_bounds__(256) void k_pack_wh(const float* __restrict__ Wh, u16* __restrict__ Wp) {
  int idx = blockIdx.x * 256 + threadIdx.x;
  if (idx >= 2359296) return;
  int j = idx & 7;
  int l = (idx >> 3) & 63;
  int t = idx >> 9;          // w*144 + nt*24 + kt
  int kt = t % 24;
  int tmp = t / 24;          // w*6 + nt
  int nt = tmp % 6, w = tmp / 6;
  int k = kt * 32 + (l >> 4) * 8 + j;
  int cc = l & 15;
  int vi = cc >> 2, q = cc & 3;
  int gcol = q * 768 + w * 24 + nt * 4 + vi;
  Wp[idx] = f2bf(Wh[(size_t)k * 3072 + gcol]);
}

// ---------- GEMM: C[16384][3072] bf16 = A[16384][768] bf16 @ Bp(packed) ----------
__global__ __launch_bounds__(256, 2) void k_gemm(const u16* __restrict__ A, const u16* __restrict__ Bp,
                                                 u16* __restrict__ C) {
  const int bid = blockIdx.x;
  const int bm = bid & 127, bn = bid >> 7;   // 128 x 24
  const int tid = threadIdx.x, lane = tid & 63, wv = tid >> 6;
  const int wm = wv >> 1, wn = wv & 1;
  const int row0 = bm * 128 + wm * 64;
  const int col0 = bn * 128 + wn * 64;
  const int rlo = lane & 15, rhi = lane >> 4;
  f32x4 acc[4][4] = {};
  const u16* Ab = A + (size_t)(row0 + rlo) * 768 + rhi * 8;
  const u16* Bb = Bp + ((size_t)(bn * 8 + wn * 4) * 24 * 64 + lane) * 8;
#pragma unroll 2
  for (int kt = 0; kt < 24; ++kt) {
    bf16x8 a[4], b[4];
#pragma unroll
    for (int i = 0; i < 4; ++i) a[i] = *(const bf16x8*)(Ab + (size_t)i * 16 * 768 + kt * 32);
#pragma unroll
    for (int j = 0; j < 4; ++j) b[j] = *(const bf16x8*)(Bb + (size_t)j * 24 * 64 * 8 + (size_t)kt * 64 * 8);
#pragma unroll
    for (int i = 0; i < 4; ++i)
#pragma unroll
      for (int j = 0; j < 4; ++j)
        acc[i][j] = __builtin_amdgcn_mfma_f32_16x16x32_bf16(a[i], b[j], acc[i][j], 0, 0, 0);
  }
#pragma unroll
  for (int i = 0; i < 4; ++i)
#pragma unroll
    for (int j = 0; j < 4; ++j)
#pragma unroll
      for (int r = 0; r < 4; ++r) {
        int row = row0 + i * 16 + rhi * 4 + r;
        int col = col0 + j * 16 + rlo;
        C[(size_t)row * 3072 + col] = f2bf(acc[i][j][r]);
      }
}

// ---------- persistent LSTM recurrence ----------
// 256 WGs x 384 threads (6 waves). Logical groups: g = wid&7 (4 seqs), member w = wid>>3 (24 units).
// Wave wv owns units [wv*4, wv*4+4): its 16 MFMA cols = 4 gates x 4 units (col = 4*vi + q).
// Per step: merged poll+fetch of tagged h_{t-1} -> stage hlds[t&1] -> ONE __syncthreads ->
// MFMA (4 indep chains) -> wave-local 16x4 transpose -> cell math -> fire-and-forget publish.
// Double-buffered hlds: stage(t+1) into buf[(t+1)&1] only races MFMA(t-1) reads of the same
// buffer, and BAR(t) separates them (every wave finished MFMA(t-1) before reaching BAR(t)).
__global__ __launch_bounds__(384) void k_rec(
    const u16* __restrict__ xg,    // [16384][3072] bf16, m = seq*512 + t
    const u16* __restrict__ Whp,   // [32][6][24][64][8] packed bf16
    const float* __restrict__ bias,
    int* hbuf,                     // [8 groups][2][3072] tagged dwords (zeroed)
    u16* __restrict__ hout_bf,     // layer 0 out (bf16) or null
    float* __restrict__ hout_f,    // layer 1 out (fp32) or null
    int layer) {
  __shared__ __align__(16) int hlds[2][4 * 400];  // double-buffered h_{t-1}[4 seq][768]
  __shared__ __align__(16) float wlds[6][68];     // per-wave 16x4 gate transpose scratch

  const int wid = blockIdx.x, g = wid & 7, w = wid >> 3;
  const int tid = threadIdx.x, lane = tid & 63, wv = tid >> 6;

  // ---- Wh fragments -> registers (static indices) ----
  bf16x8 bregE[12], bregO[12];
  {
    const u16* bp = Whp + (((size_t)(w * 6 + wv) * 24) * 64 + lane) * 8;
#pragma unroll
    for (int kk = 0; kk < 12; ++kk) {
      bregE[kk] = *(const bf16x8*)(bp + (size_t)(2 * kk) * 512);
      bregO[kk] = *(const bf16x8*)(bp + (size_t)(2 * kk + 1) * 512);
    }
  }

  // ---- cell role: lanes 0-15 of each wave own cell (seq r, unit vi) ----
  const bool cellt = lane < 16;
  const int vi = lane & 3, r = (lane >> 2) & 3;
  const int unit = w * 24 + wv * 4 + vi;
  const int seq = g * 4 + r;
  float bv0 = 0, bv1 = 0, bv2 = 0, bv3 = 0, xv0 = 0, xv1 = 0, xv2 = 0, xv3 = 0;
  if (cellt) {
    bv0 = bias[unit]; bv1 = bias[768 + unit]; bv2 = bias[1536 + unit]; bv3 = bias[2304 + unit];
    const u16* xr = xg + (size_t)seq * 512 * 3072;
    xv0 = bf2f(xr[unit]); xv1 = bf2f(xr[768 + unit]);
    xv2 = bf2f(xr[1536 + unit]); xv3 = bf2f(xr[2304 + unit]);
  }
  float cst = 0.f;
  const int sl = (lane & 15) < 4 ? (lane & 15) : 3;      // A-frag row (pad rows clamped)
  const int abase = sl * 400 + (lane >> 4) * 4;          // A-frag dword base within buffer
  const int c = tid;                                     // poll chunk id (8 dwords)
  const int hrow = c / 96, hcol = (c % 96) * 4;          // staged int4 slot
  int guard = 0;

  __syncthreads();

  for (int t = 0; t < 512; ++t) {
    int* hb = hlds[t & 1];
    // ---- merged poll+fetch of h_{t-1}: full tagged load IS the poll (1 RT) ----
    const int expect = t;  // tag written by step t-1 producers (t=0: zeroed buffer)
    int* src = hbuf + (size_t)(g * 2 + (t & 1)) * 3072;
    const int* p0 = src + 8 * c;
    const int* p1 = src + 8 * c + 4;
    i32x4 v0, v1;
    for (;;) {
      asm volatile("global_load_dwordx4 %0, %2, off sc0 sc1\n\t"
                   "global_load_dwordx4 %1, %3, off sc0 sc1\n\t"
                   "s_waitcnt vmcnt(0)"
                   : "=&v"(v0), "=&v"(v1)
                   : "v"(p0), "v"(p1)
                   : "memory");
      bool ok = true;
#pragma unroll
      for (int j = 0; j < 4; ++j)
        ok = ok && ((v0[j] & 0xffff) == expect) && ((v1[j] & 0xffff) == expect);
      if (ok || ++guard > (1 << 22)) break;
    }
    // stage packed bf16 pairs into hlds[t&1]
    {
      int4 pk;
      pk.x = (int)(((unsigned)v0[0] >> 16) | ((unsigned)v0[1] & 0xffff0000u));
      pk.y = (int)(((unsigned)v0[2] >> 16) | ((unsigned)v0[3] & 0xffff0000u));
      pk.z = (int)(((unsigned)v1[0] >> 16) | ((unsigned)v1[1] & 0xffff0000u));
      pk.w = (int)(((unsigned)v1[2] >> 16) | ((unsigned)v1[3] & 0xffff0000u));
      *(int4*)&hb[hrow * 400 + hcol] = pk;
    }
    __syncthreads();  // hlds[t&1] ready (also fences next step's staging vs MFMA(t-1))

    // ---- MFMA: gates[4 seq][16 cols of wave tile], 4 independent chains of 6 ----
    f32x4 a0 = {0, 0, 0, 0}, a1 = {0, 0, 0, 0}, a2 = {0, 0, 0, 0}, a3 = {0, 0, 0, 0};
#pragma unroll
    for (int kk = 0; kk < 12; kk += 2) {
      bf16x8 e0 = *(const bf16x8*)(hb + abase + (2 * kk) * 16);
      bf16x8 o0 = *(const bf16x8*)(hb + abase + (2 * kk + 1) * 16);
      bf16x8 e1 = *(const bf16x8*)(hb + abase + (2 * kk + 2) * 16);
      bf16x8 o1 = *(const bf16x8*)(hb + abase + (2 * kk + 3) * 16);
      a0 = __builtin_amdgcn_mfma_f32_16x16x32_bf16(e0, bregE[kk], a0, 0, 0, 0);
      a1 = __builtin_amdgcn_mfma_f32_16x16x32_bf16(o0, bregO[kk], a1, 0, 0, 0);
      a2 = __builtin_amdgcn_mfma_f32_16x16x32_bf16(e1, bregE[kk + 1], a2, 0, 0, 0);
      a3 = __builtin_amdgcn_mfma_f32_16x16x32_bf16(o1, bregO[kk + 1], a3, 0, 0, 0);
    }
    a0 = (a0 + a2) + (a1 + a3);

    // ---- wave-local 16x4 transpose -> cell lanes (no WG barrier) ----
    if (cellt) {
#pragma unroll
      for (int rr = 0; rr < 4; ++rr) wlds[wv][rr * 16 + lane] = a0[rr];
    }
    asm volatile("s_waitcnt lgkmcnt(0)" ::: "memory");
    if (cellt) {
      f32x4 tr = *(const f32x4*)&wlds[wv][r * 16 + vi * 4];  // gates i,f,g,o
      float p0g = xv0 + tr[0] + bv0;
      float p1g = xv1 + tr[1] + bv1;
      float p2g = xv2 + tr[2] + bv2;
      float p3g = xv3 + tr[3] + bv3;
      float ig = sigm(p0g), fg = sigm(p1g), gg = tanh_f(p2g), og = sigm(p3g);
      cst = fg * cst + ig * gg;
      float h = og * tanh_f(cst);
      // publish tagged h (fire-and-forget; dword atomicity makes it self-validating)
      int* dst = hbuf + (size_t)(g * 2 + ((t + 1) & 1)) * 3072 + r * 768 + unit;
      int val = (int)(((unsigned)f2bf(h) << 16) | (unsigned)(t + 1));
      __hip_atomic_store(dst, val, __ATOMIC_RELAXED, AGENT);
      // off the critical path: output store + next-step xg prefetch
      size_t o = ((size_t)seq * 512 + t) * 768 + unit;
      if (layer == 0) hout_bf[o] = f2bf(h); else hout_f[o] = h;
      if (t + 1 < 512) {
        const u16* xr = xg + ((size_t)seq * 512 + t + 1) * 3072;
        xv0 = bf2f(xr[unit]); xv1 = bf2f(xr[768 + unit]);
        xv2 = bf2f(xr[1536 + unit]); xv3 = bf2f(xr[2304 + unit]);
      }
    }
  }
}

// ---------- LayerNorm (in-place safe) ----------
__global__ __launch_bounds__(256) void k_ln(const float* __restrict__ in, const float* __restrict__ sc,
                                            const float* __restrict__ bi, float* __restrict__ out) {
  const int row = blockIdx.x, tid = threadIdx.x;
  const float* x = in + (size_t)row * 768;
  float v0 = x[tid], v1 = x[tid + 256], v2 = x[tid + 512];
  float s = v0 + v1 + v2;
  float s2 = v0 * v0 + v1 * v1 + v2 * v2;
#pragma unroll
  for (int off = 32; off >= 1; off >>= 1) {
    s += __shfl_xor(s, off);
    s2 += __shfl_xor(s2, off);
  }
  __shared__ float red[8];
  const int wv = tid >> 6;
  if ((tid & 63) == 0) { red[wv] = s; red[4 + wv] = s2; }
  __syncthreads();
  s = red[0] + red[1] + red[2] + red[3];
  s2 = red[4] + red[5] + red[6] + red[7];
  float mean = s * (1.f / 768.f);
  float var = s2 * (1.f / 768.f) - mean * mean;
  float rs = rsqrtf(var + 1e-6f);
  float* o = out + (size_t)row * 768;
  o[tid] = (v0 - mean) * rs * sc[tid] + bi[tid];
  o[tid + 256] = (v1 - mean) * rs * sc[tid + 256] + bi[tid + 256];
  o[tid + 512] = (v2 - mean) * rs * sc[tid + 512] + bi[tid + 512];
}

extern "C" void kernel_launch(void* const* d_in, const int* in_sizes, int n_in,
                              void* d_out, int out_size, void* d_ws, size_t ws_size,
                              hipStream_t stream) {
  const float* x   = (const float*)d_in[0];
  const float* Wx0 = (const float*)d_in[1];
  const float* Wh0 = (const float*)d_in[2];
  const float* b0  = (const float*)d_in[3];
  const float* Wx1 = (const float*)d_in[4];
  const float* Wh1 = (const float*)d_in[5];
  const float* b1  = (const float*)d_in[6];
  const float* lns = (const float*)d_in[7];
  const float* lnb = (const float*)d_in[8];
  float* out = (float*)d_out;

  char* p = (char*)d_ws;
  auto alloc = [&](size_t bytes) {
    char* r = p;
    p += (bytes + 255) & ~(size_t)255;
    return r;
  };
  u16* xg    = (u16*)alloc(16384ull * 3072 * 2);
  u16* xbf   = (u16*)alloc(16384ull * 768 * 2);
  u16* h0bf  = (u16*)alloc(16384ull * 768 * 2);
  u16* Wxp0  = (u16*)alloc(2359296ull * 2);
  u16* Wxp1  = (u16*)alloc(2359296ull * 2);
  u16* Whp0  = (u16*)alloc(2359296ull * 2);
  u16* Whp1  = (u16*)alloc(2359296ull * 2);
  char* sync0 = alloc(196608ull * 2);   // hbuf0, hbuf1 (tagged dwords)
  int* hbuf0 = (int*)sync0;
  int* hbuf1 = (int*)(sync0 + 196608);

  if ((size_t)(p - (char*)d_ws) > ws_size) {
    fprintf(stderr, "kernel_launch: ws too small: need %zu have %zu\n",
            (size_t)(p - (char*)d_ws), ws_size);
    return;
  }

  hipMemsetAsync(sync0, 0, 196608ull * 2, stream);
  k_cvt<<<12288, 256, 0, stream>>>(x, xbf, 3145728);
  k_pack_wx<<<9216, 256, 0, stream>>>(Wx0, Wxp0);
  k_pack_wx<<<9216, 256, 0, stream>>>(Wx1, Wxp1);
  k_pack_wh<<<9216, 256, 0, stream>>>(Wh0, Whp0);
  k_pack_wh<<<9216, 256, 0, stream>>>(Wh1, Whp1);

  k_gemm<<<3072, 256, 0, stream>>>(xbf, Wxp0, xg);
  k_rec<<<256, 384, 0, stream>>>(xg, Whp0, b0, hbuf0, h0bf, nullptr, 0);
  k_gemm<<<3072, 256, 0, stream>>>(h0bf, Wxp1, xg);
  k_rec<<<256, 384, 0, stream>>>(xg, Whp1, b1, hbuf1, nullptr, (float*)d_out, 1);
  k_ln<<<16384, 256, 0, stream>>>((const float*)d_out, lns, lnb, out);
}